// Round 8
// baseline (29.741 us; speedup 1.0000x reference)
//
#include <hip/hip_runtime.h>

#define NPTS 2048
#define CCH  256
#define CAP  256   // per-wave compaction capacity; E[valid]~134, sigma~11 (11-sigma margin)

// ---- DPP cross-lane helpers (VALU pipe, no LDS) ----
template <int CTRL>
__device__ __forceinline__ float dppf(float v) {
    return __int_as_float(__builtin_amdgcn_update_dpp(
        0, __float_as_int(v), CTRL, 0xF, 0xF, true));
}
__device__ __forceinline__ float row16_max(float v) {
    v = fmaxf(v, dppf<0xB1>(v));
    v = fmaxf(v, dppf<0x4E>(v));
    v = fmaxf(v, dppf<0x141>(v));
    v = fmaxf(v, dppf<0x140>(v));
    return v;
}
__device__ __forceinline__ float row16_min(float v) {
    v = fminf(v, dppf<0xB1>(v));
    v = fminf(v, dppf<0x4E>(v));
    v = fminf(v, dppf<0x141>(v));
    v = fminf(v, dppf<0x140>(v));
    return v;
}
__device__ __forceinline__ float row16_sum(float v) {
    v += dppf<0xB1>(v);
    v += dppf<0x4E>(v);
    v += dppf<0x141>(v);
    v += dppf<0x140>(v);
    return v;
}
__device__ __forceinline__ float wave_sum(float v) {
    v = row16_sum(v);
    v += __shfl_xor(v, 16, 64);
    v += __shfl_xor(v, 32, 64);
    return v;
}

// ws layout (floats): [0..767] W_eff (256x3 row-major), [768..1023] b_eff

// ---------------------------------------------------------------------------
// Merged prep: W_eff = (W3*W2)*W1, b_eff = (W3*W2)*b1 + W3*b2 + b3.
// Block o: M[o][c] via LDS-broadcast W3 row + coalesced W2 column reads.
// 8 partial accumulators -> 8 outstanding L2 loads (prep is latency-bound at
// 4 waves/CU; ILP is the only latency hiding available).
// ---------------------------------------------------------------------------
__global__ __launch_bounds__(256) void prep_kernel(
    const float* __restrict__ w1, const float* __restrict__ b1,
    const float* __restrict__ w2, const float* __restrict__ b2,
    const float* __restrict__ w3, const float* __restrict__ b3,
    float* __restrict__ ws)
{
    __shared__ float  w3row[CCH];
    __shared__ float4 wpart[4];
    int o = blockIdx.x, c = threadIdx.x;

    float w3c = w3[o * CCH + c];         // coalesced
    w3row[c] = w3c;
    __syncthreads();

    float a0 = 0.f, a1 = 0.f, a2 = 0.f, a3 = 0.f;
    float a4 = 0.f, a5 = 0.f, a6 = 0.f, a7 = 0.f;
    const float* w2c = w2 + c;
    for (int k = 0; k < CCH; k += 8) {
        a0 = fmaf(w3row[k + 0], w2c[(k + 0) * CCH], a0);
        a1 = fmaf(w3row[k + 1], w2c[(k + 1) * CCH], a1);
        a2 = fmaf(w3row[k + 2], w2c[(k + 2) * CCH], a2);
        a3 = fmaf(w3row[k + 3], w2c[(k + 3) * CCH], a3);
        a4 = fmaf(w3row[k + 4], w2c[(k + 4) * CCH], a4);
        a5 = fmaf(w3row[k + 5], w2c[(k + 5) * CCH], a5);
        a6 = fmaf(w3row[k + 6], w2c[(k + 6) * CCH], a6);
        a7 = fmaf(w3row[k + 7], w2c[(k + 7) * CCH], a7);
    }
    float acc = ((a0 + a1) + (a2 + a3)) + ((a4 + a5) + (a6 + a7));   // M[o][c]

    float4 v = make_float4(acc * w1[c * 3 + 0],
                           acc * w1[c * 3 + 1],
                           acc * w1[c * 3 + 2],
                           fmaf(acc, b1[c], w3c * b2[c]));
    v.x = wave_sum(v.x);
    v.y = wave_sum(v.y);
    v.z = wave_sum(v.z);
    v.w = wave_sum(v.w);
    if ((c & 63) == 0) wpart[c >> 6] = v;
    __syncthreads();
    if (c == 0) {
        float4 p0 = wpart[0], p1 = wpart[1], p2 = wpart[2], p3 = wpart[3];
        ws[o * 3 + 0] = (p0.x + p1.x) + (p2.x + p3.x);
        ws[o * 3 + 1] = (p0.y + p1.y) + (p2.y + p3.y);
        ws[o * 3 + 2] = (p0.z + p1.z) + (p2.z + p3.z);
        ws[3 * CCH + o] = (p0.w + p1.w) + (p2.w + p3.w) + b3[o];
    }
}

// ---------------------------------------------------------------------------
// pointsift: 256 threads = 4 waves = 4 points/block; no barrier, no coord
// stage. Pass-1 compacts via LDS ATOMIC counter (no ballot/mbcnt chain ->
// iterations fully independent), storing (dx,dy,dz,idx) packed in float4.
// Selection is lexicographic on (d2, original index) everywhere, so the
// atomic's nondeterministic list order cannot affect the output.
// LDS = 4*256*16B + counters ~= 16.4 KB -> 8 blocks/CU.
// ---------------------------------------------------------------------------
__global__ __launch_bounds__(256, 8) void pointsift_kernel(
    const float* __restrict__ x,   // [Bp, NPTS, 3]
    const float* __restrict__ ws,  // W_eff[256*3] then b_eff[256]
    float* __restrict__ out)       // [Bp, NPTS, 21]
{
    __shared__ float4 sl[4][CAP];                  // 16 KB: (dx,dy,dz, idx_bits)
    __shared__ unsigned scnt[4];

    int batch = blockIdx.x & 3;
    int n0    = (blockIdx.x >> 2) * 4;
    const float* xb = x + (size_t)batch * NPTS * 3;

    int wave = threadIdx.x >> 6;
    int lane = threadIdx.x & 63;
    int n = n0 + wave;

    if (lane == 0) scnt[wave] = 0;                 // same-wave LDS order: safe

    float3 cpt = *(const float3*)(xb + 3 * n);
    float cx = cpt.x, cy = cpt.y, cz = cpt.z;

    float4* slw = sl[wave];

    // ---- pass 1: validity + atomic compaction (independent iterations) ----
#pragma unroll 4
    for (int m = lane; m < NPTS; m += 64) {
        float3 p = *(const float3*)(xb + 3 * m);
        float dx = p.x - cx, dy = p.y - cy, dz = p.z - cz;
        // bit-match numpy: (dx*dx + dy*dy) + dz*dz, no FMA contraction
        float d2 = __fadd_rn(__fadd_rn(__fmul_rn(dx, dx), __fmul_rn(dy, dy)),
                             __fmul_rn(dz, dz));
        if ((d2 > 1e-10f) && (d2 < 0.0625f)) {
            unsigned ps = atomicAdd(&scnt[wave], 1u);
            if (ps < CAP)
                slw[ps] = make_float4(dx, dy, dz, __uint_as_float((unsigned)m));
        }
    }

    unsigned cnt = scnt[wave];                     // after this wave's atomics

    // ---- pass 2: per-octant lexicographic best (d2, then original index) ----
    float bd[8];
    int   bi[8];
#pragma unroll
    for (int i = 0; i < 8; ++i) { bd[i] = __builtin_inff(); bi[i] = n; }

    if (cnt <= CAP) {
        int cn = (int)cnt;
        for (int t = lane; t < cn; t += 64) {
            float4 e = slw[t];
            float dx = e.x, dy = e.y, dz = e.z;
            int m = (int)__float_as_uint(e.w);
            float d2 = __fadd_rn(__fadd_rn(__fmul_rn(dx, dx), __fmul_rn(dy, dy)),
                                 __fmul_rn(dz, dz));
            // exact octant per reference: trunc(d+1.0) in {0,1}
            int oct = 4 * (int)(dx + 1.0f) + 2 * (int)(dy + 1.0f) + (int)(dz + 1.0f);
#pragma unroll
            for (int i = 0; i < 8; ++i) {
                bool upd = (oct == i) &&
                           ((d2 < bd[i]) || ((d2 == bd[i]) && (m < bi[i])));
                bd[i] = upd ? d2 : bd[i];
                bi[i] = upd ? m : bi[i];
            }
        }
    } else {
        // 11-sigma-rare overflow; exact deterministic fallback: full rescan
        for (int m = lane; m < NPTS; m += 64) {
            float3 p = *(const float3*)(xb + 3 * m);
            float dx = p.x - cx, dy = p.y - cy, dz = p.z - cz;
            float d2 = __fadd_rn(__fadd_rn(__fmul_rn(dx, dx), __fmul_rn(dy, dy)),
                                 __fmul_rn(dz, dz));
            bool valid = (d2 > 1e-10f) && (d2 < 0.0625f);
            int oct = 4 * (int)(dx + 1.0f) + 2 * (int)(dy + 1.0f) + (int)(dz + 1.0f);
#pragma unroll
            for (int i = 0; i < 8; ++i) {
                bool upd = valid && (oct == i) &&
                           ((d2 < bd[i]) || ((d2 == bd[i]) && (m < bi[i])));
                bd[i] = upd ? d2 : bd[i];
                bi[i] = upd ? m : bi[i];
            }
        }
    }

    // ---- cross-lane argmin: DPP min + 2 swizzles; lex tie-break (min index) ----
    int nidx[8];
#pragma unroll
    for (int i = 0; i < 8; ++i) {
        float mv = row16_min(bd[i]);
        mv = fminf(mv, __shfl_xor(mv, 16, 64));
        mv = fminf(mv, __shfl_xor(mv, 32, 64));
        unsigned long long mk = __ballot(bd[i] == mv);   // wave-uniform
        if (__popcll(mk) == 1) {
            nidx[i] = __builtin_amdgcn_readlane(bi[i], (int)__builtin_ctzll(mk));
        } else {
            // ties (or empty octant: mv=inf, all lanes match, bi=n everywhere)
            int mm = (bd[i] == mv) ? bi[i] : 0x7FFFFFFF;
#pragma unroll
            for (int s = 32; s > 0; s >>= 1) {
                int o = __shfl_xor(mm, s, 64);
                mm = o < mm ? o : mm;
            }
            nidx[i] = mm;
        }
    }

    // ---- fused affine + SPP: lane handles channels 4*lane..4*lane+3 ----
    const float4* wsv = (const float4*)ws;
    float4 wa = wsv[lane * 3 + 0];
    float4 wb = wsv[lane * 3 + 1];
    float4 wc = wsv[lane * 3 + 2];
    float4 be = ((const float4*)(ws + 3 * CCH))[lane];
    float w[4][3] = {{wa.x, wa.y, wa.z}, {wa.w, wb.x, wb.y},
                     {wb.z, wb.w, wc.x}, {wc.y, wc.z, wc.w}};
    float bev[4] = {be.x, be.y, be.z, be.w};

    float m16[4];
#pragma unroll
    for (int i = 0; i < 4; ++i) m16[i] = -__builtin_inff();
#pragma unroll
    for (int k = 0; k < 8; ++k) {
        float3 p = *(const float3*)(xb + 3 * nidx[k]);  // wave-uniform L1 read
        float gx = p.x - cx, gy = p.y - cy, gz = p.z - cz;
#pragma unroll
        for (int q = 0; q < 4; ++q) {
            float h = fmaf(gx, w[q][0], fmaf(gy, w[q][1], fmaf(gz, w[q][2], bev[q])));
            m16[k >> 1] = fmaxf(m16[k >> 1], h);
        }
    }

    float t[4], u[4];
#pragma unroll
    for (int i = 0; i < 4; ++i) {
        m16[i] = row16_max(m16[i]);
        t[i] = fmaxf(m16[i], __shfl_xor(m16[i], 16, 64));
        u[i] = fmaxf(t[i], __shfl_xor(t[i], 32, 64));
    }

    float* op = out + ((size_t)batch * NPTS + n) * 21;
    if ((lane & 15) == 0) {
        int j = lane >> 4;
#pragma unroll
        for (int i = 0; i < 4; ++i)
            op[i * 4 + j] = m16[i];
    }
    if (lane == 0 || lane == 32) {
        int j2 = lane >> 5;
        op[16 + 0 * 2 + j2] = fmaxf(t[0], t[1]);
        op[16 + 1 * 2 + j2] = fmaxf(t[2], t[3]);
    }
    if (lane == 0) {
        op[20] = fmaxf(fmaxf(u[0], u[1]), fmaxf(u[2], u[3]));
    }
}

extern "C" void kernel_launch(void* const* d_in, const int* in_sizes, int n_in,
                              void* d_out, int out_size, void* d_ws, size_t ws_size,
                              hipStream_t stream) {
    const float* x  = (const float*)d_in[0];
    const float* w1 = (const float*)d_in[1];
    const float* b1 = (const float*)d_in[2];
    const float* w2 = (const float*)d_in[3];
    const float* b2 = (const float*)d_in[4];
    const float* w3 = (const float*)d_in[5];
    const float* b3 = (const float*)d_in[6];
    float* out = (float*)d_out;
    float* ws  = (float*)d_ws;

    prep_kernel<<<CCH, CCH, 0, stream>>>(w1, b1, w2, b2, w3, b3, ws);

    int Bp = in_sizes[0] / (NPTS * 3);             // B*T = 4
    pointsift_kernel<<<Bp * (NPTS / 4), 256, 0, stream>>>(x, ws, out);
}